// Round 3
// baseline (72.019 us; speedup 1.0000x reference)
//
#include <hip/hip_runtime.h>
#include <limits.h>

#define BATCH 512
#define SEQ   8192
#define KLEN  8
// Priority key: (5-n)*SEQ + p. Smaller key = longer n, then earlier p.
// "No match" sentinel: 0x7F7F7F7F (memset-able, > 3*SEQ).
#define KEY_LIMIT (3 * SEQ)   // any real key is < 3*SEQ = 24576

// One block = one 1024-position tile of one row. 256 thr x 4 pos, no loop.
__global__ __launch_bounds__(256)
void ngram_scan(const int* __restrict__ num_tokens,
                const int* __restrict__ tokens,
                int* __restrict__ best)          // [B] in d_ws, init 0x7F
{
    const int b = blockIdx.y;
    const int L = num_tokens[b];
    const int limit3 = L - 3 - KLEN;
    const int limit4 = L - 4 - KLEN;
    const int limit5 = L - 5 - KLEN;
    const int p_begin = blockIdx.x * 1024;
    if (p_begin > limit3) return;            // whole tile past valid range
    // Here limit3 >= 0  =>  L >= 11, so pattern indices L-5..L-1 are safe.
    const long base = (long)b * SEQ;
    const int pat0 = tokens[base + L - 5];
    const int pat1 = tokens[base + L - 4];
    const int pat2 = tokens[base + L - 3];
    const int pat3 = tokens[base + L - 2];
    const int pat4 = tokens[base + L - 1];

    int bestLocal = INT_MAX;
    const int p0 = p_begin + (int)threadIdx.x * 4;
    if (p0 <= limit3) {
        // p0 <= limit3 <= SEQ-12 -> p0+7 <= SEQ-5: both loads in-row.
        const int4 va = *(const int4*)(tokens + base + p0);
        const int4 vb = *(const int4*)(tokens + base + p0 + 4);
        const int w[8] = { va.x, va.y, va.z, va.w, vb.x, vb.y, vb.z, vb.w };
        #pragma unroll
        for (int j = 0; j < 4; ++j) {
            const int p = p0 + j;
            const bool q3 = (w[j]   == pat2) & (w[j+1] == pat3) & (w[j+2] == pat4)
                            & (p <= limit3);
            const bool q4 = (w[j]   == pat1) & (w[j+1] == pat2) & (w[j+2] == pat3)
                            & (w[j+3] == pat4) & (p <= limit4);
            const bool q5 = (w[j]   == pat0) & (w[j+1] == pat1) & (w[j+2] == pat2)
                            & (w[j+3] == pat3) & (w[j+4] == pat4) & (p <= limit5);
            if (q3) bestLocal = min(bestLocal, 2 * SEQ + p);
            if (q4) bestLocal = min(bestLocal, 1 * SEQ + p);
            if (q5) bestLocal = min(bestLocal, p);
        }
    }
    if (bestLocal != INT_MAX) atomicMin(&best[b], bestLocal);  // device-scope
}

// 4096 threads: thread t -> row t>>3, element t&7.
__global__ __launch_bounds__(256)
void ngram_extract(const int* __restrict__ tokens,
                   const int* __restrict__ mask,     // bool canonicalized int32
                   const int* __restrict__ best,
                   int* __restrict__ out)            // [B,K]
{
    const int t = blockIdx.x * 256 + (int)threadIdx.x;
    const int b = t >> 3;
    const int k = t & 7;
    const int key = best[b];
    int v = 0;
    if (key < KEY_LIMIT && mask[b] != 0) {
        const int n = 5 - (key >> 13);       // key / SEQ
        const int p = key & (SEQ - 1);       // key % SEQ
        // p <= L-n-K  ->  p+n+k <= L-1 < SEQ: in bounds.
        v = tokens[(long)b * SEQ + p + n + k];
    }
    out[t] = v;   // always write: d_out is re-poisoned each call
}

extern "C" void kernel_launch(void* const* d_in, const int* in_sizes, int n_in,
                              void* d_out, int out_size, void* d_ws, size_t ws_size,
                              hipStream_t stream) {
    const int* num_tokens = (const int*)d_in[0];   // [B] int32
    const int* token_ids  = (const int*)d_in[1];   // [B,S] int32
    const int* cmask      = (const int*)d_in[2];   // [B] bool -> int32
    int* out              = (int*)d_out;           // [B,K] int32
    int* best             = (int*)d_ws;            // [B] scratch keys

    // 0x7F7F7F7F > KEY_LIMIT: serves as "no match" sentinel for atomicMin.
    hipMemsetAsync(best, 0x7F, BATCH * sizeof(int), stream);

    dim3 grid_scan(SEQ / 1024, BATCH);             // 8 x 512 blocks
    ngram_scan<<<grid_scan, 256, 0, stream>>>(num_tokens, token_ids, best);

    ngram_extract<<<(BATCH * KLEN) / 256, 256, 0, stream>>>(token_ids, cmask,
                                                            best, out);
}

// Round 4
// 69.262 us; speedup vs baseline: 1.0398x; 1.0398x over previous
//
#include <hip/hip_runtime.h>
#include <limits.h>

#define BATCH 512
#define SEQ   8192
#define KLEN  8
// Priority key: (5-n)*SEQ + p. Smaller key = longer n first, then earlier p —
// matches the reference's length-major selection (n=5 > 4 > 3, first match).
#define KEY_LIMIT (3 * SEQ)

// ONE dispatch does everything: scan + priority-select + extract.
// One block per row; 1024 thr x 4 positions x 2 iterations covers S=8192.
// 512 blocks -> 2 blocks/CU, 32 waves/CU (full occupancy).
__global__ __launch_bounds__(1024)
void ngram_fused(const int* __restrict__ num_tokens,   // [B]
                 const int* __restrict__ tokens,       // [B,S]
                 const int* __restrict__ mask,         // [B] bool as int32
                 int* __restrict__ out)                // [B,K]
{
    const int b   = blockIdx.x;
    const int tid = threadIdx.x;
    const int L   = num_tokens[b];
    const long base = (long)b * SEQ;

    __shared__ int s_best;
    if (tid == 0) s_best = INT_MAX;
    __syncthreads();

    const int limit3 = L - 3 - KLEN;
    const int limit4 = L - 4 - KLEN;
    const int limit5 = L - 5 - KLEN;

    int pat0 = 0, pat1 = 0, pat2 = 0, pat3 = 0, pat4 = 0;
    if (limit3 >= 0) {           // L >= 11 -> indices L-5..L-1 all valid
        pat0 = tokens[base + L - 5];
        pat1 = tokens[base + L - 4];
        pat2 = tokens[base + L - 3];
        pat3 = tokens[base + L - 2];
        pat4 = tokens[base + L - 1];
    }

    int bestLocal = INT_MAX;
    // p0 <= limit3 <= 8180 -> p0+8 <= L-3 < SEQ: both int4 loads in-row,
    // 16B-aligned (p0 % 4 == 0).
    for (int p0 = tid * 4; p0 <= limit3; p0 += 4096) {
        const int4 va = *(const int4*)(tokens + base + p0);
        const int4 vb = *(const int4*)(tokens + base + p0 + 4);
        const int w[8] = { va.x, va.y, va.z, va.w, vb.x, vb.y, vb.z, vb.w };
        #pragma unroll
        for (int j = 0; j < 4; ++j) {
            const int p = p0 + j;
            const bool q3 = (w[j]   == pat2) & (w[j+1] == pat3) & (w[j+2] == pat4)
                            & (p <= limit3);
            const bool q4 = (w[j]   == pat1) & (w[j+1] == pat2) & (w[j+2] == pat3)
                            & (w[j+3] == pat4) & (p <= limit4);
            const bool q5 = (w[j]   == pat0) & (w[j+1] == pat1) & (w[j+2] == pat2)
                            & (w[j+3] == pat3) & (w[j+4] == pat4) & (p <= limit5);
            if (q3) bestLocal = min(bestLocal, 2 * SEQ + p);
            if (q4) bestLocal = min(bestLocal, 1 * SEQ + p);
            if (q5) bestLocal = min(bestLocal, p);
        }
    }
    // Matches are rare (~1e-4/position): LDS atomic traffic ~0.
    if (bestLocal != INT_MAX) atomicMin(&s_best, bestLocal);
    __syncthreads();

    if (tid < KLEN) {
        const int key = s_best;
        int v = 0;
        if (key < KEY_LIMIT && mask[b] != 0) {
            const int n = 5 - (key >> 13);   // key / SEQ
            const int p = key & (SEQ - 1);   // key % SEQ
            // p <= L-n-K -> p+n+tid <= L-1 < SEQ
            v = tokens[base + p + n + tid];
        }
        out[b * KLEN + tid] = v;   // always write: d_out is re-poisoned
    }
}

extern "C" void kernel_launch(void* const* d_in, const int* in_sizes, int n_in,
                              void* d_out, int out_size, void* d_ws, size_t ws_size,
                              hipStream_t stream) {
    const int* num_tokens = (const int*)d_in[0];   // [B] int32
    const int* token_ids  = (const int*)d_in[1];   // [B,S] int32
    const int* cmask      = (const int*)d_in[2];   // [B] bool -> int32
    int* out              = (int*)d_out;           // [B,K] int32

    ngram_fused<<<BATCH, 1024, 0, stream>>>(num_tokens, token_ids, cmask, out);
}

// Round 5
// 68.697 us; speedup vs baseline: 1.0484x; 1.0082x over previous
//
#include <hip/hip_runtime.h>
#include <limits.h>

#define BATCH 512
#define SEQ   8192
#define KLEN  8
// Priority key: (5-n)*SEQ + p. Smaller key = longer n first, then earlier p —
// matches the reference's length-major selection (n=5 > 4 > 3, first match).
#define KEY_LIMIT (3 * SEQ)

// ONE dispatch: scan + priority-select + extract.
// One block per row; 1024 thr x 8 positions = 8192 = S in a single pass.
// 3x int4 loads per thread (12 tokens for 8 windows) = 1.5x amplification.
__global__ __launch_bounds__(1024)
void ngram_fused(const int* __restrict__ num_tokens,   // [B]
                 const int* __restrict__ tokens,       // [B,S]
                 const int* __restrict__ mask,         // [B] bool as int32
                 int* __restrict__ out)                // [B,K]
{
    const int b   = blockIdx.x;
    const int tid = threadIdx.x;
    const int mk  = mask[b];          // independent scalar loads, overlap
    const int L   = num_tokens[b];
    const long base = (long)b * SEQ;

    __shared__ int s_best;
    if (tid == 0) s_best = INT_MAX;

    const int limit3 = L - 3 - KLEN;  // max valid p for n=3
    const int limit4 = L - 4 - KLEN;
    const int limit5 = L - 5 - KLEN;

    // Block-uniform early out: masked-off row or row too short -> output is
    // all zeros regardless of matches. (Reference zeroes masked rows.)
    if (mk == 0 || limit3 < 0) {
        if (tid < KLEN) out[b * KLEN + tid] = 0;
        return;                       // uniform: no barrier divergence
    }
    __syncthreads();                  // s_best init visible

    // L >= 11 here -> pattern indices L-5..L-1 valid. Same-address across
    // the block -> broadcast from L1.
    const int pat0 = tokens[base + L - 5];
    const int pat1 = tokens[base + L - 4];
    const int pat2 = tokens[base + L - 3];
    const int pat3 = tokens[base + L - 2];
    const int pat4 = tokens[base + L - 1];

    int bestLocal = INT_MAX;
    const int p0 = tid * 8;           // 16B-aligned; covers p0..p0+7
    if (p0 <= limit3) {
        // p0 <= limit3 = L-11 -> p0+11 <= L-1 < SEQ: all three loads in-row.
        const int4 va = *(const int4*)(tokens + base + p0);
        const int4 vb = *(const int4*)(tokens + base + p0 + 4);
        const int4 vc = *(const int4*)(tokens + base + p0 + 8);
        const int w[12] = { va.x, va.y, va.z, va.w,
                            vb.x, vb.y, vb.z, vb.w,
                            vc.x, vc.y, vc.z, vc.w };
        #pragma unroll
        for (int j = 0; j < 8; ++j) {
            const int p = p0 + j;
            const bool q3 = (w[j]   == pat2) & (w[j+1] == pat3) & (w[j+2] == pat4)
                            & (p <= limit3);
            const bool q4 = (w[j]   == pat1) & (w[j+1] == pat2) & (w[j+2] == pat3)
                            & (w[j+3] == pat4) & (p <= limit4);
            const bool q5 = (w[j]   == pat0) & (w[j+1] == pat1) & (w[j+2] == pat2)
                            & (w[j+3] == pat3) & (w[j+4] == pat4) & (p <= limit5);
            if (q3) bestLocal = min(bestLocal, 2 * SEQ + p);
            if (q4) bestLocal = min(bestLocal, 1 * SEQ + p);
            if (q5) bestLocal = min(bestLocal, p);
        }
    }
    // Matches are rare (~1e-4/position): LDS atomic traffic ~0.
    if (bestLocal != INT_MAX) atomicMin(&s_best, bestLocal);
    __syncthreads();

    if (tid < KLEN) {
        const int key = s_best;
        int v = 0;
        if (key < KEY_LIMIT) {               // mask already known nonzero
            const int n = 5 - (key >> 13);   // key / SEQ
            const int p = key & (SEQ - 1);   // key % SEQ
            // p <= L-n-K -> p+n+tid <= L-1 < SEQ
            v = tokens[base + p + n + tid];
        }
        out[b * KLEN + tid] = v;   // always write: d_out is re-poisoned
    }
}

extern "C" void kernel_launch(void* const* d_in, const int* in_sizes, int n_in,
                              void* d_out, int out_size, void* d_ws, size_t ws_size,
                              hipStream_t stream) {
    const int* num_tokens = (const int*)d_in[0];   // [B] int32
    const int* token_ids  = (const int*)d_in[1];   // [B,S] int32
    const int* cmask      = (const int*)d_in[2];   // [B] bool -> int32
    int* out              = (int*)d_out;           // [B,K] int32

    ngram_fused<<<BATCH, 1024, 0, stream>>>(num_tokens, token_ids, cmask, out);
}